// Round 7
// baseline (782.735 us; speedup 1.0000x reference)
//
#include <hip/hip_runtime.h>
#include <math.h>

// Problem constants
#define BDIM 4096
#define NEXP 8
#define HDIM 1024
#define XDIM 800
#define ZDIM 64
#define ODIM 768
#define GH   128

typedef _Float16 f16;
typedef f16   f16x8 __attribute__((ext_vector_type(8)));
typedef f16   f16x4 __attribute__((ext_vector_type(4)));
typedef float f32x4 __attribute__((ext_vector_type(4)));

__device__ __forceinline__ float elu_act(float x) {
    return x > 0.0f ? x : expm1f(x);
}

__device__ __forceinline__ f16x8 vscale(f16x8 v, f16 s) {
    f16x8 r;
    #pragma unroll
    for (int i = 0; i < 8; ++i) r[i] = v[i] * s;
    return r;
}

// ===========================================================================
// fp32 tiled GEMM with implicit concat input (gating MLP only — small)
// ===========================================================================
#define BMg 64
#define BNg 64
#define BKg 32
#define PADg 68

template<int ACT>
__global__ __launch_bounds__(256)
void gemm_cat(const float* __restrict__ srcA, int KH,
              const float* __restrict__ srcZ, int KZ,
              const float* __restrict__ W, const float* __restrict__ bias,
              float* __restrict__ dst, int N)
{
    __shared__ float lds_a[BKg][PADg];
    __shared__ float lds_b[BKg][PADg];
    const int K = KH + KZ;
    const int row0 = blockIdx.x * BMg;
    const int col0 = blockIdx.y * BNg;
    const int tid = threadIdx.x;
    const int tx = tid & 15, ty = tid >> 4;

    float acc[4][4] = {};

    for (int k0 = 0; k0 < K; k0 += BKg) {
        #pragma unroll
        for (int it = 0; it < 2; ++it) {
            int idx = tid + it * 256;
            int r = idx >> 3;
            int f = idx & 7;
            int k = k0 + f * 4;
            const float* src; int col;
            if (k < KH) { src = srcA + (size_t)(row0 + r) * KH; col = k; }
            else        { src = srcZ + (size_t)(row0 + r) * KZ; col = k - KH; }
            float4 v = *(const float4*)(src + col);
            lds_a[f*4+0][r] = v.x; lds_a[f*4+1][r] = v.y;
            lds_a[f*4+2][r] = v.z; lds_a[f*4+3][r] = v.w;
        }
        #pragma unroll
        for (int it = 0; it < 2; ++it) {
            int idx = tid + it * 256;
            int c = idx >> 3;
            int f = idx & 7;
            int k = k0 + f * 4;
            float4 v = *(const float4*)(W + (size_t)(col0 + c) * K + k);
            lds_b[f*4+0][c] = v.x; lds_b[f*4+1][c] = v.y;
            lds_b[f*4+2][c] = v.z; lds_b[f*4+3][c] = v.w;
        }
        __syncthreads();
        #pragma unroll
        for (int j = 0; j < BKg; ++j) {
            float4 a4 = *(const float4*)&lds_a[j][ty*4];
            float4 b4 = *(const float4*)&lds_b[j][tx*4];
            float a[4] = {a4.x, a4.y, a4.z, a4.w};
            float b[4] = {b4.x, b4.y, b4.z, b4.w};
            #pragma unroll
            for (int i = 0; i < 4; ++i)
                #pragma unroll
                for (int jj = 0; jj < 4; ++jj)
                    acc[i][jj] += a[i] * b[jj];
        }
        __syncthreads();
    }

    #pragma unroll
    for (int i = 0; i < 4; ++i) {
        int r = row0 + ty*4 + i;
        float vals[4];
        #pragma unroll
        for (int j = 0; j < 4; ++j) {
            float v = acc[i][j] + bias[col0 + tx*4 + j];
            vals[j] = (ACT == 1) ? elu_act(v) : v;
        }
        *(float4*)(dst + (size_t)r * N + col0 + tx*4) =
            make_float4(vals[0], vals[1], vals[2], vals[3]);
    }
}

// ===========================================================================
// Gating layer 3 + softmax (fp32)
// ===========================================================================
__global__ __launch_bounds__(256)
void gating3_softmax(const float* __restrict__ g2, const float* __restrict__ Wg3,
                     const float* __restrict__ bg3, float* __restrict__ bc)
{
    __shared__ float w[NEXP * GH];
    __shared__ float bsh[NEXP];
    const int tid = threadIdx.x;
    for (int i = tid; i < NEXP * GH; i += 256) w[i] = Wg3[i];
    if (tid < NEXP) bsh[tid] = bg3[tid];
    __syncthreads();

    const int rowl = tid >> 3;
    const int o    = tid & 7;
    const int row  = blockIdx.x * 32 + rowl;
    const float* g = g2 + (size_t)row * GH;

    float s = bsh[o];
    for (int k = 0; k < GH; ++k) s += g[k] * w[o * GH + k];

    float m = s;
    #pragma unroll
    for (int d = 4; d >= 1; d >>= 1) m = fmaxf(m, __shfl_xor(m, d, 8));
    float e = expf(s - m);
    float sum = e;
    #pragma unroll
    for (int d = 4; d >= 1; d >>= 1) sum += __shfl_xor(sum, d, 8);

    bc[(size_t)blockIdx.x * 256 + tid] = e / sum;
}

// ===========================================================================
// Activation-tiling helpers.
// Tiled activation layout (same idea as the weight tiling):
//   At[(rt*KC + kc)*512 + lane*8 + j] = A[rt*16 + (lane&15)][kc*32 + (lane>>4)*8 + j]
// A wave's A-frag is then a contiguous, coalesced 1 KB global read.
// ===========================================================================

// build tiled xz16 (K=864, KC=27) from fp32 x,z
__global__ __launch_bounds__(256)
void xz_tile(const float* __restrict__ x, const float* __restrict__ z,
             f16* __restrict__ At)
{
    size_t i = (size_t)blockIdx.x * 256 + threadIdx.x;  // one 16B chunk each
    int lane = (int)(i & 63);
    size_t t = i >> 6;
    int kc = (int)(t % 27);
    int rt = (int)(t / 27);
    int m = rt * 16 + (lane & 15);
    int k = kc * 32 + (lane >> 4) * 8;
    const float* s = (k < XDIM) ? x + (size_t)m * XDIM + k
                                : z + (size_t)m * ZDIM + (k - XDIM);
    float4 v0 = *(const float4*)s;
    float4 v1 = *(const float4*)(s + 4);
    f16x8 o = { (f16)v0.x,(f16)v0.y,(f16)v0.z,(f16)v0.w,
                (f16)v1.x,(f16)v1.y,(f16)v1.z,(f16)v1.w };
    *(f16x8*)(At + i * 8) = o;
}

// fill z-chunks (kc=32,33 of KC=34) of one tiled hz buffer
__global__ __launch_bounds__(256)
void fill_z_tiled(const float* __restrict__ z, f16* __restrict__ At)
{
    int i = blockIdx.x * 256 + threadIdx.x;             // over 4096*64/8 chunks
    int lane = i & 63;
    int c = i >> 6;
    int rt  = c >> 1;
    int kcz = c & 1;
    int m  = rt * 16 + (lane & 15);
    int kz = kcz * 32 + (lane >> 4) * 8;                // z col 0..63
    const float* s = z + (size_t)m * ZDIM + kz;
    float4 v0 = *(const float4*)s;
    float4 v1 = *(const float4*)(s + 4);
    f16x8 o = { (f16)v0.x,(f16)v0.y,(f16)v0.z,(f16)v0.w,
                (f16)v1.x,(f16)v1.y,(f16)v1.z,(f16)v1.w };
    *(f16x8*)(At + ((size_t)(rt * 34 + 32 + kcz) * 64 + lane) * 8) = o;
}

// ===========================================================================
// Weight conversion fp32 -> f16 in MFMA B-frag tiled layout:
//   Wt[((e*(N/16) + nt)*KC + kc)*512 + lane*8 + j]
//     = W[e][nt*16 + (lane&15)][kc*32 + (lane>>4)*8 + j]
// ===========================================================================
template<int N, int K>
__global__ __launch_bounds__(256)
void w_tile(const float* __restrict__ W, f16* __restrict__ Wt)
{
    constexpr int KC = K / 32;
    size_t i = (size_t)blockIdx.x * 256 + threadIdx.x;   // one 16B chunk each
    int lane = (int)(i & 63);
    size_t t = i >> 6;
    int kc = (int)(t % KC);
    int nt = (int)((t / KC) % (N / 16));
    int e  = (int)(t / KC / (N / 16));
    const float* s = W + ((size_t)e * N + nt * 16 + (lane & 15)) * K
                       + kc * 32 + (lane >> 4) * 8;
    float4 v0 = *(const float4*)s;
    float4 v1 = *(const float4*)(s + 4);
    f16x8 o = { (f16)v0.x,(f16)v0.y,(f16)v0.z,(f16)v0.w,
                (f16)v1.x,(f16)v1.y,(f16)v1.z,(f16)v1.w };
    *(f16x8*)(Wt + i * 8) = o;
}

// ===========================================================================
// Blended expert layer v5 — BARRIER-FREE K-loop:
//   out[b,o] = act( sum_e (bc[b,e]*A[b,:]) . W[e,o,:] + sum_e bc[b,e]*bias[e,o] )
// Both A and W are pre-tiled into MFMA fragment layout, so the K-loop is a
// pure global-load + MFMA stream: no LDS, no __syncthreads, no vmcnt(0)
// drains. B-frags prefetched 2 experts ahead; next k-step's A-frags issued at
// the top of each k-step (full-k-step latency cover).
// Block 128x128 = 4 waves side-by-side (each 128M x 32N = mt 8 x nt 2).
// Grid (N/128, 32): XCD = blockIdx.x%8 -> per-XCD weight slice 2.2 MB (L2).
// Epilogue OMODE 0: wave-private LDS transpose -> tiled-A f16 output.
//         OMODE 1: plain fp32 row-major output.
// ===========================================================================
template<int KCA, int KLOOP, int N, int ACT, int OMODE, int KCOUT, typename OT>
__global__ __launch_bounds__(256, 1)
void blended_v5(const f16* __restrict__ At,
                const f16* __restrict__ Wt, const float* __restrict__ bias,
                const float* __restrict__ bc, OT* __restrict__ out, int ldOut)
{
    __shared__ float bc_sh[128][8];
    __shared__ float bias_sh[8][128];
    __shared__ f16 t_sh[4][16][32];      // wave-private transpose scratch

    const int tid  = threadIdx.x;
    const int col0 = blockIdx.x * 128;
    const int row0 = blockIdx.y * 128;
    const int wave = tid >> 6;           // n-position (4 waves x 32 cols)
    const int lane = tid & 63;
    const int ln   = lane & 15;
    const int quad = lane >> 4;

    // stage bc tile [128][8] and bias tile [8][128]
    for (int i = tid; i < 128 * 8; i += 256)
        bc_sh[i >> 3][i & 7] = bc[(size_t)(row0 + (i >> 3)) * NEXP + (i & 7)];
    for (int i = tid; i < 8 * 128; i += 256)
        bias_sh[i >> 7][i & 127] = bias[(size_t)(i >> 7) * N + col0 + (i & 127)];
    __syncthreads();     // the ONLY block-wide barrier

    // per-lane f16 bc scales for A-frag rows (m = mt*16 + ln)
    f16 bcf[8][8];
    #pragma unroll
    for (int mt = 0; mt < 8; ++mt)
        #pragma unroll
        for (int e = 0; e < 8; ++e)
            bcf[mt][e] = (f16)bc_sh[mt * 16 + ln][e];

    // A-frag base pointers per mt (tiled layout, KCA chunk stride)
    const f16* ap[8];
    #pragma unroll
    for (int mt = 0; mt < 8; ++mt)
        ap[mt] = At + ((size_t)(row0 / 16 + mt) * KCA) * 512 + lane * 8;

    // B-frag pointers for this wave's two n-tiles
    constexpr size_t ESTR = (size_t)(N / 16) * KLOOP * 512;  // expert stride
    const f16* wp0 = Wt + ((size_t)(col0 / 16 + wave * 2 + 0) * KLOOP) * 512 + lane * 8;
    const f16* wp1 = Wt + ((size_t)(col0 / 16 + wave * 2 + 1) * KLOOP) * 512 + lane * 8;

    f32x4 acc[8][2] = {};

    // prime pipelines: A-frags for ks=0, B-frags for (ks=0, e=0) and (0,1)
    f16x8 afc[8];
    #pragma unroll
    for (int mt = 0; mt < 8; ++mt) afc[mt] = *(const f16x8*)(ap[mt]);

    f16x8 b0a = *(const f16x8*)(wp0);
    f16x8 b1a = *(const f16x8*)(wp1);
    f16x8 b0b = *(const f16x8*)(wp0 + ESTR);
    f16x8 b1b = *(const f16x8*)(wp1 + ESTR);

    for (int ks = 0; ks < KLOOP; ++ks) {
        // prefetch next k-step's A-frags (covered by full k-step of compute)
        f16x8 afn[8];
        #pragma unroll
        for (int mt = 0; mt < 8; ++mt)
            afn[mt] = *(const f16x8*)(ap[mt] + (size_t)(ks + 1) * 512);

        #pragma unroll
        for (int e = 0; e < 8; ++e) {
            // prefetch B-frags 2 experts ahead (wraps into next k-step);
            // tail reads stay in-bounds (land in low-e chunks) and are unused.
            const int ks2 = (e < 6) ? ks : ks + 1;
            const int e2  = (e + 2) & 7;
            f16x8 nb0 = *(const f16x8*)(wp0 + (size_t)e2 * ESTR + (size_t)ks2 * 512);
            f16x8 nb1 = *(const f16x8*)(wp1 + (size_t)e2 * ESTR + (size_t)ks2 * 512);

            #pragma unroll
            for (int mt = 0; mt < 8; ++mt) {
                f16x8 s = vscale(afc[mt], bcf[mt][e]);
                acc[mt][0] = __builtin_amdgcn_mfma_f32_16x16x32_f16(s, b0a, acc[mt][0], 0,0,0);
                acc[mt][1] = __builtin_amdgcn_mfma_f32_16x16x32_f16(s, b1a, acc[mt][1], 0,0,0);
            }
            b0a = b0b; b1a = b1b;
            b0b = nb0; b1b = nb1;
        }

        #pragma unroll
        for (int mt = 0; mt < 8; ++mt) afc[mt] = afn[mt];
    }

    // ---------------- epilogue ----------------
    if (OMODE == 1) {
        // plain fp32 row-major
        #pragma unroll
        for (int mt = 0; mt < 8; ++mt)
            #pragma unroll
            for (int r = 0; r < 4; ++r) {
                int rl = mt * 16 + quad * 4 + r;
                size_t grow = (size_t)(row0 + rl) * ldOut;
                #pragma unroll
                for (int nt = 0; nt < 2; ++nt) {
                    int cl = wave * 32 + nt * 16 + ln;
                    float v = acc[mt][nt][r];
                    #pragma unroll
                    for (int e2 = 0; e2 < NEXP; ++e2)
                        v += bc_sh[rl][e2] * bias_sh[e2][cl];
                    if (ACT) v = elu_act(v);
                    out[grow + col0 + cl] = (OT)v;
                }
            }
    } else {
        // tiled-A f16 output via wave-private LDS transpose (no barriers)
        f16* tb = &t_sh[wave][0][0];
        const int kc_out = col0 / 32 + wave;
        #pragma unroll
        for (int mt = 0; mt < 8; ++mt) {
            #pragma unroll
            for (int nt = 0; nt < 2; ++nt) {
                int cl = wave * 32 + nt * 16 + ln;
                #pragma unroll
                for (int r = 0; r < 4; ++r) {
                    int rl = mt * 16 + quad * 4 + r;
                    float v = acc[mt][nt][r];
                    #pragma unroll
                    for (int e2 = 0; e2 < NEXP; ++e2)
                        v += bc_sh[rl][e2] * bias_sh[e2][cl];
                    if (ACT) v = elu_act(v);
                    tb[(quad * 4 + r) * 32 + nt * 16 + ln] = (f16)v;
                }
            }
            // same-wave LDS RAW: compiler inserts lgkmcnt wait
            f16x8 o = *(const f16x8*)&tb[(lane & 15) * 32 + (lane >> 4) * 8];
            *(f16x8*)((f16*)out +
                ((size_t)(row0 / 16 + mt) * KCOUT + kc_out) * 512 + lane * 8) = o;
        }
    }
}

// ===========================================================================
extern "C" void kernel_launch(void* const* d_in, const int* in_sizes, int n_in,
                              void* d_out, int out_size, void* d_ws, size_t ws_size,
                              hipStream_t stream)
{
    const float* x   = (const float*)d_in[0];
    const float* z   = (const float*)d_in[1];
    const float* Wg1 = (const float*)d_in[2];
    const float* bg1 = (const float*)d_in[3];
    const float* Wg2 = (const float*)d_in[4];
    const float* bg2 = (const float*)d_in[5];
    const float* Wg3 = (const float*)d_in[6];
    const float* bg3 = (const float*)d_in[7];
    const float* W0  = (const float*)d_in[8];
    const float* b0  = (const float*)d_in[9];
    const float* W1  = (const float*)d_in[10];
    const float* b1  = (const float*)d_in[11];
    const float* W2  = (const float*)d_in[12];
    const float* b2  = (const float*)d_in[13];
    const float* W3  = (const float*)d_in[14];
    const float* b3  = (const float*)d_in[15];
    float* out = (float*)d_out;

    // workspace (~35.7 MB):
    //   wbuf  f16 [8*1024*1088]  (per-layer tiled weights; holds g1/g2 fp32
    //                             during gating — dead before first w_tile)
    //   hz_a  f16 [4096*1088]    (tiled activations, KC=34)
    //   hz_b  f16 [4096*1088]    (tiled; ALSO aliases xz_t f16[4096*864]
    //                             which is dead after layer 0)
    //   bcw   f32 [4096*8]
    char* ws = (char*)d_ws;
    f16*   wbuf = (f16*)ws;                 ws += (size_t)NEXP * HDIM * (HDIM + ZDIM) * 2;
    f16*   hz_a = (f16*)ws;                 ws += (size_t)BDIM * (HDIM + ZDIM) * 2;
    f16*   hz_b = (f16*)ws;                 ws += (size_t)BDIM * (HDIM + ZDIM) * 2;
    float* bcw  = (float*)ws;

    float* g1   = (float*)wbuf;
    float* g2   = g1 + (size_t)BDIM * GH;
    f16*   xz_t = hz_b;                     // alias: xz dead before L1 writes hz_b

    dim3 blk(256);

    // tiled layer-0 input + hz_a z-chunks
    xz_tile<<<dim3(BDIM * (XDIM + ZDIM) / 8 / 256), blk, 0, stream>>>(x, z, xz_t);
    fill_z_tiled<<<dim3(BDIM * ZDIM / 8 / 256), blk, 0, stream>>>(z, hz_a);

    // gating MLP (fp32) — g1/g2 live inside wbuf region (dead before w_tile)
    gemm_cat<1><<<dim3(BDIM/BMg, GH/BNg), blk, 0, stream>>>(x, XDIM, z, ZDIM, Wg1, bg1, g1, GH);
    gemm_cat<1><<<dim3(BDIM/BMg, GH/BNg), blk, 0, stream>>>(g1, GH, nullptr, 0, Wg2, bg2, g2, GH);
    gating3_softmax<<<dim3(BDIM/32), blk, 0, stream>>>(g2, Wg3, bg3, bcw);

    // layer 0: xz_t (KCA=27) -> hz_a (tiled, KCOUT=34)
    w_tile<HDIM, XDIM+ZDIM><<<dim3(NEXP*HDIM*(XDIM+ZDIM)/2048), blk, 0, stream>>>(W0, wbuf);
    blended_v5<27, 27, HDIM, 1, 0, 34, f16><<<dim3(HDIM/128, BDIM/128), blk, 0, stream>>>(
        xz_t, wbuf, b0, bcw, hz_a, 0);

    // hz_b z-chunks (xz_t alias now dead)
    fill_z_tiled<<<dim3(BDIM * ZDIM / 8 / 256), blk, 0, stream>>>(z, hz_b);

    // layer 1: hz_a -> hz_b
    w_tile<HDIM, HDIM+ZDIM><<<dim3(NEXP*HDIM*(HDIM+ZDIM)/2048), blk, 0, stream>>>(W1, wbuf);
    blended_v5<34, 34, HDIM, 1, 0, 34, f16><<<dim3(HDIM/128, BDIM/128), blk, 0, stream>>>(
        hz_a, wbuf, b1, bcw, hz_b, 0);

    // layer 2: hz_b -> hz_a
    w_tile<HDIM, HDIM+ZDIM><<<dim3(NEXP*HDIM*(HDIM+ZDIM)/2048), blk, 0, stream>>>(W2, wbuf);
    blended_v5<34, 34, HDIM, 1, 0, 34, f16><<<dim3(HDIM/128, BDIM/128), blk, 0, stream>>>(
        hz_b, wbuf, b2, bcw, hz_a, 0);

    // layer 3: hz_a (KCA=34, K=1024) -> out fp32 row-major
    w_tile<ODIM, HDIM><<<dim3(NEXP*ODIM*HDIM/2048), blk, 0, stream>>>(W3, wbuf);
    blended_v5<34, 32, ODIM, 0, 1, 0, float><<<dim3(ODIM/128, BDIM/128), blk, 0, stream>>>(
        hz_a, wbuf, b3, bcw, out, ODIM);
}

// Round 8
// 664.785 us; speedup vs baseline: 1.1774x; 1.1774x over previous
//
#include <hip/hip_runtime.h>
#include <math.h>

// Problem constants
#define BDIM 4096
#define NEXP 8
#define HDIM 1024
#define XDIM 800
#define ZDIM 64
#define ODIM 768
#define GH   128

typedef _Float16 f16;
typedef f16   f16x8 __attribute__((ext_vector_type(8)));
typedef f16   f16x4 __attribute__((ext_vector_type(4)));
typedef float f32x4 __attribute__((ext_vector_type(4)));

__device__ __forceinline__ float elu_act(float x) {
    return x > 0.0f ? x : expm1f(x);
}

__device__ __forceinline__ f16x8 vscale(f16x8 v, f16 s) {
    f16x8 r;
    #pragma unroll
    for (int i = 0; i < 8; ++i) r[i] = v[i] * s;
    return r;
}

// ===========================================================================
// fp32 tiled GEMM with implicit concat input (gating MLP only — small)
// ===========================================================================
#define BMg 64
#define BNg 64
#define BKg 32
#define PADg 68

template<int ACT>
__global__ __launch_bounds__(256)
void gemm_cat(const float* __restrict__ srcA, int KH,
              const float* __restrict__ srcZ, int KZ,
              const float* __restrict__ W, const float* __restrict__ bias,
              float* __restrict__ dst, int N)
{
    __shared__ float lds_a[BKg][PADg];
    __shared__ float lds_b[BKg][PADg];
    const int K = KH + KZ;
    const int row0 = blockIdx.x * BMg;
    const int col0 = blockIdx.y * BNg;
    const int tid = threadIdx.x;
    const int tx = tid & 15, ty = tid >> 4;

    float acc[4][4] = {};

    for (int k0 = 0; k0 < K; k0 += BKg) {
        #pragma unroll
        for (int it = 0; it < 2; ++it) {
            int idx = tid + it * 256;
            int r = idx >> 3;
            int f = idx & 7;
            int k = k0 + f * 4;
            const float* src; int col;
            if (k < KH) { src = srcA + (size_t)(row0 + r) * KH; col = k; }
            else        { src = srcZ + (size_t)(row0 + r) * KZ; col = k - KH; }
            float4 v = *(const float4*)(src + col);
            lds_a[f*4+0][r] = v.x; lds_a[f*4+1][r] = v.y;
            lds_a[f*4+2][r] = v.z; lds_a[f*4+3][r] = v.w;
        }
        #pragma unroll
        for (int it = 0; it < 2; ++it) {
            int idx = tid + it * 256;
            int c = idx >> 3;
            int f = idx & 7;
            int k = k0 + f * 4;
            float4 v = *(const float4*)(W + (size_t)(col0 + c) * K + k);
            lds_b[f*4+0][c] = v.x; lds_b[f*4+1][c] = v.y;
            lds_b[f*4+2][c] = v.z; lds_b[f*4+3][c] = v.w;
        }
        __syncthreads();
        #pragma unroll
        for (int j = 0; j < BKg; ++j) {
            float4 a4 = *(const float4*)&lds_a[j][ty*4];
            float4 b4 = *(const float4*)&lds_b[j][tx*4];
            float a[4] = {a4.x, a4.y, a4.z, a4.w};
            float b[4] = {b4.x, b4.y, b4.z, b4.w};
            #pragma unroll
            for (int i = 0; i < 4; ++i)
                #pragma unroll
                for (int jj = 0; jj < 4; ++jj)
                    acc[i][jj] += a[i] * b[jj];
        }
        __syncthreads();
    }

    #pragma unroll
    for (int i = 0; i < 4; ++i) {
        int r = row0 + ty*4 + i;
        float vals[4];
        #pragma unroll
        for (int j = 0; j < 4; ++j) {
            float v = acc[i][j] + bias[col0 + tx*4 + j];
            vals[j] = (ACT == 1) ? elu_act(v) : v;
        }
        *(float4*)(dst + (size_t)r * N + col0 + tx*4) =
            make_float4(vals[0], vals[1], vals[2], vals[3]);
    }
}

// ===========================================================================
// Gating layer 3 + softmax (fp32)
// ===========================================================================
__global__ __launch_bounds__(256)
void gating3_softmax(const float* __restrict__ g2, const float* __restrict__ Wg3,
                     const float* __restrict__ bg3, float* __restrict__ bc)
{
    __shared__ float w[NEXP * GH];
    __shared__ float bsh[NEXP];
    const int tid = threadIdx.x;
    for (int i = tid; i < NEXP * GH; i += 256) w[i] = Wg3[i];
    if (tid < NEXP) bsh[tid] = bg3[tid];
    __syncthreads();

    const int rowl = tid >> 3;
    const int o    = tid & 7;
    const int row  = blockIdx.x * 32 + rowl;
    const float* g = g2 + (size_t)row * GH;

    float s = bsh[o];
    for (int k = 0; k < GH; ++k) s += g[k] * w[o * GH + k];

    float m = s;
    #pragma unroll
    for (int d = 4; d >= 1; d >>= 1) m = fmaxf(m, __shfl_xor(m, d, 8));
    float e = expf(s - m);
    float sum = e;
    #pragma unroll
    for (int d = 4; d >= 1; d >>= 1) sum += __shfl_xor(sum, d, 8);

    bc[(size_t)blockIdx.x * 256 + tid] = e / sum;
}

// ===========================================================================
// Activation tiling:
//   At[(rt*KC + kc)*512 + lane*8 + j] = A[rt*16 + (lane&15)][kc*32 + (lane>>4)*8 + j]
// ===========================================================================
__global__ __launch_bounds__(256)
void xz_tile(const float* __restrict__ x, const float* __restrict__ z,
             f16* __restrict__ At)
{
    size_t i = (size_t)blockIdx.x * 256 + threadIdx.x;  // one 16B chunk each
    int lane = (int)(i & 63);
    size_t t = i >> 6;
    int kc = (int)(t % 27);
    int rt = (int)(t / 27);
    int m = rt * 16 + (lane & 15);
    int k = kc * 32 + (lane >> 4) * 8;
    const float* s = (k < XDIM) ? x + (size_t)m * XDIM + k
                                : z + (size_t)m * ZDIM + (k - XDIM);
    float4 v0 = *(const float4*)s;
    float4 v1 = *(const float4*)(s + 4);
    f16x8 o = { (f16)v0.x,(f16)v0.y,(f16)v0.z,(f16)v0.w,
                (f16)v1.x,(f16)v1.y,(f16)v1.z,(f16)v1.w };
    *(f16x8*)(At + i * 8) = o;
}

// fill z-chunks (kc=32,33 of KC=34) of one tiled hz buffer
__global__ __launch_bounds__(256)
void fill_z_tiled(const float* __restrict__ z, f16* __restrict__ At)
{
    int i = blockIdx.x * 256 + threadIdx.x;
    int lane = i & 63;
    int c = i >> 6;
    int rt  = c >> 1;
    int kcz = c & 1;
    int m  = rt * 16 + (lane & 15);
    int kz = kcz * 32 + (lane >> 4) * 8;
    const float* s = z + (size_t)m * ZDIM + kz;
    float4 v0 = *(const float4*)s;
    float4 v1 = *(const float4*)(s + 4);
    f16x8 o = { (f16)v0.x,(f16)v0.y,(f16)v0.z,(f16)v0.w,
                (f16)v1.x,(f16)v1.y,(f16)v1.z,(f16)v1.w };
    *(f16x8*)(At + ((size_t)(rt * 34 + 32 + kcz) * 64 + lane) * 8) = o;
}

// ===========================================================================
// Weight conversion fp32 -> f16, tiled [nt][kc][e] (expert-innermost so the
// K-loop's B stream is perfectly sequential):
//   Wt[((nt*KC + kc)*8 + e)*512 + lane*8 + j]
//     = W[e][nt*16 + (lane&15)][kc*32 + (lane>>4)*8 + j]
// ===========================================================================
template<int N, int K>
__global__ __launch_bounds__(256)
void w_tile(const float* __restrict__ W, f16* __restrict__ Wt)
{
    constexpr int KC = K / 32;
    size_t i = (size_t)blockIdx.x * 256 + threadIdx.x;   // one 16B chunk each
    int lane = (int)(i & 63);
    size_t t = i >> 6;
    int e  = (int)(t & 7);
    int kc = (int)((t >> 3) % KC);
    int nt = (int)((t >> 3) / KC);
    const float* s = W + ((size_t)e * N + nt * 16 + (lane & 15)) * K
                       + kc * 32 + (lane >> 4) * 8;
    float4 v0 = *(const float4*)s;
    float4 v1 = *(const float4*)(s + 4);
    f16x8 o = { (f16)v0.x,(f16)v0.y,(f16)v0.z,(f16)v0.w,
                (f16)v1.x,(f16)v1.y,(f16)v1.z,(f16)v1.w };
    *(f16x8*)(Wt + i * 8) = o;
}

// ===========================================================================
// Blended expert layer v6 — barrier-free K-loop at 2 waves/SIMD:
//   out[b,o] = act( sum_e (bc[b,e]*A[b,:]) . W[e,o,:] + sum_e bc[b,e]*bias[e,o] )
// Wave tile 128M x 16N (mt=8, nt=1): 2048 wave-tiles -> 2 waves/SIMD (the
// occupancy that v4/v5 lacked). B stream is sequential (Wt is [nt][kc][e])
// with a rolling 3-deep register prefetch queue (~930 cyc cover). A-frags
// register-prefetched one full k-step ahead. No LDS, no barriers in the loop.
// Block = 4 waves side by side (128M x 64N); grid (N/64, 32) = 512 blocks,
// 2 blocks/CU; XCD = blockIdx.x%8 keeps each XCD's weight slice <= 3.1 MB.
// ===========================================================================
template<int KCA, int KLOOP, int N, int ACT, int OMODE, int KCOUT, typename OT>
__global__ __launch_bounds__(256, 2)
void blended_v6(const f16* __restrict__ At,
                const f16* __restrict__ Wt, const float* __restrict__ bias,
                const float* __restrict__ bc, OT* __restrict__ out, int ldOut)
{
    __shared__ float bc_sh[128][8];
    __shared__ float bias_sh[8][64];
    __shared__ f16 ep_sh[16 * 512];      // epilogue retile staging (OMODE 0)

    const int tid  = threadIdx.x;
    const int col0 = blockIdx.x * 64;
    const int row0 = blockIdx.y * 128;
    const int wave = tid >> 6;           // n-stripe: cols [wave*16, wave*16+16)
    const int lane = tid & 63;
    const int ln   = lane & 15;
    const int quad = lane >> 4;

    for (int i = tid; i < 128 * 8; i += 256)
        bc_sh[i >> 3][i & 7] = bc[(size_t)(row0 + (i >> 3)) * NEXP + (i & 7)];
    for (int i = tid; i < 8 * 64; i += 256)
        bias_sh[i >> 6][i & 63] = bias[(size_t)(i >> 6) * N + col0 + (i & 63)];
    __syncthreads();

    // per-lane f16 bc scales for A-frag rows (m = mt*16 + ln)
    f16 bcf[8][8];
    #pragma unroll
    for (int mt = 0; mt < 8; ++mt)
        #pragma unroll
        for (int e = 0; e < 8; ++e)
            bcf[mt][e] = (f16)bc_sh[mt * 16 + ln][e];

    // A-frag (mt, ks) at ap + (mt*KCA + ks)*512
    const f16* ap = At + ((size_t)(row0 / 16) * KCA) * 512 + lane * 8;
    // B-frag (ks, e) at wp + (ks*8 + e)*512  — fully sequential stream
    const f16* wp = Wt + ((size_t)(col0 / 16 + wave) * KLOOP * 8) * 512 + lane * 8;

    f32x4 acc[8] = {};

    f16x8 afc[8];
    #pragma unroll
    for (int mt = 0; mt < 8; ++mt)
        afc[mt] = *(const f16x8*)(ap + (size_t)mt * KCA * 512);

    // rolling 3-deep B prefetch queue
    f16x8 bq0 = *(const f16x8*)(wp);
    f16x8 bq1 = *(const f16x8*)(wp + 512);
    f16x8 bq2 = *(const f16x8*)(wp + 1024);

    for (int ks = 0; ks < KLOOP; ++ks) {
        // next k-step's A-frags (full k-step of latency cover)
        f16x8 afn[8];
        #pragma unroll
        for (int mt = 0; mt < 8; ++mt)
            afn[mt] = *(const f16x8*)(ap + ((size_t)mt * KCA + ks + 1) * 512);

        #pragma unroll
        for (int e = 0; e < 8; ++e) {
            // prefetch B 3 steps ahead (sequential address; tail reads land
            // in the next n-tile's data — in-bounds of the workspace, unused)
            f16x8 nb = *(const f16x8*)(wp + (size_t)(ks * 8 + e + 3) * 512);
            #pragma unroll
            for (int mt = 0; mt < 8; ++mt) {
                f16x8 s = vscale(afc[mt], bcf[mt][e]);
                acc[mt] = __builtin_amdgcn_mfma_f32_16x16x32_f16(s, bq0, acc[mt], 0, 0, 0);
            }
            bq0 = bq1; bq1 = bq2; bq2 = nb;
        }

        #pragma unroll
        for (int mt = 0; mt < 8; ++mt) afc[mt] = afn[mt];
    }

    // ---------------- epilogue ----------------
    const int bcol = wave * 16 + ln;     // block-local output column
    if (OMODE == 1) {
        #pragma unroll
        for (int mt = 0; mt < 8; ++mt)
            #pragma unroll
            for (int r = 0; r < 4; ++r) {
                int rl = mt * 16 + quad * 4 + r;
                float v = acc[mt][r];
                #pragma unroll
                for (int e2 = 0; e2 < NEXP; ++e2)
                    v += bc_sh[rl][e2] * bias_sh[e2][bcol];
                if (ACT) v = elu_act(v);
                out[(size_t)(row0 + rl) * ldOut + col0 + bcol] = (OT)v;
            }
    } else {
        // stage as tiled-A chunks in LDS, then block-cooperative copy-out
        const int c_kcl = bcol >> 5;           // which 32-col chunk (0/1)
        const int cc    = bcol & 31;           // col within chunk
        #pragma unroll
        for (int mt = 0; mt < 8; ++mt) {
            #pragma unroll
            for (int r = 0; r < 4; ++r) {
                int rl = mt * 16 + quad * 4 + r;
                float v = acc[mt][r];
                #pragma unroll
                for (int e2 = 0; e2 < NEXP; ++e2)
                    v += bc_sh[rl][e2] * bias_sh[e2][bcol];
                if (ACT) v = elu_act(v);
                ep_sh[(mt * 2 + c_kcl) * 512 + (cc >> 3) * 128
                      + (quad * 4 + r) * 8 + (cc & 7)] = (f16)v;
            }
        }
        __syncthreads();
        #pragma unroll
        for (int it = 0; it < 4; ++it) {
            int idx = tid + it * 256;          // over 16 chunks x 64 lanes
            int ch = idx >> 6;
            int l  = idx & 63;
            f16x8 v = *(const f16x8*)&ep_sh[ch * 512 + l * 8];
            size_t g = ((size_t)(row0 / 16 + (ch >> 1)) * KCOUT
                        + (col0 / 32 + (ch & 1))) * 512 + l * 8;
            *(f16x8*)((f16*)out + g) = v;
        }
    }
}

// ===========================================================================
extern "C" void kernel_launch(void* const* d_in, const int* in_sizes, int n_in,
                              void* d_out, int out_size, void* d_ws, size_t ws_size,
                              hipStream_t stream)
{
    const float* x   = (const float*)d_in[0];
    const float* z   = (const float*)d_in[1];
    const float* Wg1 = (const float*)d_in[2];
    const float* bg1 = (const float*)d_in[3];
    const float* Wg2 = (const float*)d_in[4];
    const float* bg2 = (const float*)d_in[5];
    const float* Wg3 = (const float*)d_in[6];
    const float* bg3 = (const float*)d_in[7];
    const float* W0  = (const float*)d_in[8];
    const float* b0  = (const float*)d_in[9];
    const float* W1  = (const float*)d_in[10];
    const float* b1  = (const float*)d_in[11];
    const float* W2  = (const float*)d_in[12];
    const float* b2  = (const float*)d_in[13];
    const float* W3  = (const float*)d_in[14];
    const float* b3  = (const float*)d_in[15];
    float* out = (float*)d_out;

    // workspace (~35.7 MB):
    //   wbuf  f16 [8*1024*1088]  tiled weights (g1/g2 fp32 alias during gating)
    //   hz_a  f16 [4096*1088]    tiled activations (KC=34)
    //   hz_b  f16 [4096*1088]    tiled; also aliases xz_t (dead after layer 0)
    //   bcw   f32 [4096*8]
    char* ws = (char*)d_ws;
    f16*   wbuf = (f16*)ws;                 ws += (size_t)NEXP * HDIM * (HDIM + ZDIM) * 2;
    f16*   hz_a = (f16*)ws;                 ws += (size_t)BDIM * (HDIM + ZDIM) * 2;
    f16*   hz_b = (f16*)ws;                 ws += (size_t)BDIM * (HDIM + ZDIM) * 2;
    float* bcw  = (float*)ws;

    float* g1   = (float*)wbuf;
    float* g2   = g1 + (size_t)BDIM * GH;
    f16*   xz_t = hz_b;                     // alias: dead before L1 writes hz_b

    dim3 blk(256);

    // tiled layer-0 input + hz_a z-chunks
    xz_tile<<<dim3(BDIM * (XDIM + ZDIM) / 8 / 256), blk, 0, stream>>>(x, z, xz_t);
    fill_z_tiled<<<dim3(BDIM * ZDIM / 8 / 256), blk, 0, stream>>>(z, hz_a);

    // gating MLP (fp32)
    gemm_cat<1><<<dim3(BDIM/BMg, GH/BNg), blk, 0, stream>>>(x, XDIM, z, ZDIM, Wg1, bg1, g1, GH);
    gemm_cat<1><<<dim3(BDIM/BMg, GH/BNg), blk, 0, stream>>>(g1, GH, nullptr, 0, Wg2, bg2, g2, GH);
    gating3_softmax<<<dim3(BDIM/32), blk, 0, stream>>>(g2, Wg3, bg3, bcw);

    // layer 0: xz_t (KCA=27) -> hz_a (tiled, KCOUT=34)
    w_tile<HDIM, XDIM+ZDIM><<<dim3(NEXP*HDIM*(XDIM+ZDIM)/2048), blk, 0, stream>>>(W0, wbuf);
    blended_v6<27, 27, HDIM, 1, 0, 34, f16><<<dim3(HDIM/64, BDIM/128), blk, 0, stream>>>(
        xz_t, wbuf, b0, bcw, hz_a, 0);

    // hz_b z-chunks (xz_t alias now dead)
    fill_z_tiled<<<dim3(BDIM * ZDIM / 8 / 256), blk, 0, stream>>>(z, hz_b);

    // layer 1: hz_a -> hz_b
    w_tile<HDIM, HDIM+ZDIM><<<dim3(NEXP*HDIM*(HDIM+ZDIM)/2048), blk, 0, stream>>>(W1, wbuf);
    blended_v6<34, 34, HDIM, 1, 0, 34, f16><<<dim3(HDIM/64, BDIM/128), blk, 0, stream>>>(
        hz_a, wbuf, b1, bcw, hz_b, 0);

    // layer 2: hz_b -> hz_a
    w_tile<HDIM, HDIM+ZDIM><<<dim3(NEXP*HDIM*(HDIM+ZDIM)/2048), blk, 0, stream>>>(W2, wbuf);
    blended_v6<34, 34, HDIM, 1, 0, 34, f16><<<dim3(HDIM/64, BDIM/128), blk, 0, stream>>>(
        hz_b, wbuf, b2, bcw, hz_a, 0);

    // layer 3: hz_a (KCA=34, K=1024) -> out fp32 row-major
    w_tile<ODIM, HDIM><<<dim3(NEXP*ODIM*HDIM/2048), blk, 0, stream>>>(W3, wbuf);
    blended_v6<34, 32, ODIM, 0, 1, 0, float><<<dim3(ODIM/64, BDIM/128), blk, 0, stream>>>(
        hz_a, wbuf, b3, bcw, out, ODIM);
}